// Round 12
// baseline (587.467 us; speedup 1.0000x reference)
//
#include <hip/hip_runtime.h>

#define NNB 32

__device__ __forceinline__ float sigmoid_fast(float x) {
    return __fdividef(1.0f, 1.0f + __expf(-x));
}

// ---- repetition macros: ALL register-array indices are compile-time
// literals (rule #20: runtime-indexed arrays go to scratch; literal-indexed
// arrays are SROA'd into scalars regardless of unroll heuristics). ----
#define LOAD16(a, s) \
  a[0]=(s)[0];   a[1]=(s)[1];   a[2]=(s)[2];   a[3]=(s)[3]; \
  a[4]=(s)[4];   a[5]=(s)[5];   a[6]=(s)[6];   a[7]=(s)[7]; \
  a[8]=(s)[8];   a[9]=(s)[9];   a[10]=(s)[10]; a[11]=(s)[11]; \
  a[12]=(s)[12]; a[13]=(s)[13]; a[14]=(s)[14]; a[15]=(s)[15];

#define FMA16(a, s, w) \
  a[0]=fmaf((s),(w)[0],a[0]);    a[1]=fmaf((s),(w)[1],a[1]); \
  a[2]=fmaf((s),(w)[2],a[2]);    a[3]=fmaf((s),(w)[3],a[3]); \
  a[4]=fmaf((s),(w)[4],a[4]);    a[5]=fmaf((s),(w)[5],a[5]); \
  a[6]=fmaf((s),(w)[6],a[6]);    a[7]=fmaf((s),(w)[7],a[7]); \
  a[8]=fmaf((s),(w)[8],a[8]);    a[9]=fmaf((s),(w)[9],a[9]); \
  a[10]=fmaf((s),(w)[10],a[10]); a[11]=fmaf((s),(w)[11],a[11]); \
  a[12]=fmaf((s),(w)[12],a[12]); a[13]=fmaf((s),(w)[13],a[13]); \
  a[14]=fmaf((s),(w)[14],a[14]); a[15]=fmaf((s),(w)[15],a[15]);

#define RELUST16(h, B, a) \
  h[(B)+0]=fmaxf(a[0],0.f);    h[(B)+1]=fmaxf(a[1],0.f); \
  h[(B)+2]=fmaxf(a[2],0.f);    h[(B)+3]=fmaxf(a[3],0.f); \
  h[(B)+4]=fmaxf(a[4],0.f);    h[(B)+5]=fmaxf(a[5],0.f); \
  h[(B)+6]=fmaxf(a[6],0.f);    h[(B)+7]=fmaxf(a[7],0.f); \
  h[(B)+8]=fmaxf(a[8],0.f);    h[(B)+9]=fmaxf(a[9],0.f); \
  h[(B)+10]=fmaxf(a[10],0.f);  h[(B)+11]=fmaxf(a[11],0.f); \
  h[(B)+12]=fmaxf(a[12],0.f);  h[(B)+13]=fmaxf(a[13],0.f); \
  h[(B)+14]=fmaxf(a[14],0.f);  h[(B)+15]=fmaxf(a[15],0.f);

#define FOLD16(w) \
  ts0=fmaf(fmaxf(acc[0],0.f),(w)[0],ts0);   ts1=fmaf(fmaxf(acc[1],0.f),(w)[1],ts1); \
  ts0=fmaf(fmaxf(acc[2],0.f),(w)[2],ts0);   ts1=fmaf(fmaxf(acc[3],0.f),(w)[3],ts1); \
  ts0=fmaf(fmaxf(acc[4],0.f),(w)[4],ts0);   ts1=fmaf(fmaxf(acc[5],0.f),(w)[5],ts1); \
  ts0=fmaf(fmaxf(acc[6],0.f),(w)[6],ts0);   ts1=fmaf(fmaxf(acc[7],0.f),(w)[7],ts1); \
  ts0=fmaf(fmaxf(acc[8],0.f),(w)[8],ts0);   ts1=fmaf(fmaxf(acc[9],0.f),(w)[9],ts1); \
  ts0=fmaf(fmaxf(acc[10],0.f),(w)[10],ts0); ts1=fmaf(fmaxf(acc[11],0.f),(w)[11],ts1); \
  ts0=fmaf(fmaxf(acc[12],0.f),(w)[12],ts0); ts1=fmaf(fmaxf(acc[13],0.f),(w)[13],ts1); \
  ts0=fmaf(fmaxf(acc[14],0.f),(w)[14],ts0); ts1=fmaf(fmaxf(acc[15],0.f),(w)[15],ts1);

// 4 k-steps consuming one float4 of input; weights advance 64 floats/row.
#define L1CHUNK(xv) \
  { const float* w_=w1p;     FMA16(acc,(xv).x,w_) } \
  { const float* w_=w1p+64;  FMA16(acc,(xv).y,w_) } \
  { const float* w_=w1p+128; FMA16(acc,(xv).z,w_) } \
  { const float* w_=w1p+192; FMA16(acc,(xv).w,w_) }

// L2 k-step: h1[(k)] is a literal index.
#define L2K(k)   { const float* w_=w2base+(k)*64; FMA16(acc, h1[(k)], w_) }
#define L2K4(k)  L2K(k) L2K((k)+1) L2K((k)+2) L2K((k)+3)
#define L2K16(k) L2K4(k) L2K4((k)+4) L2K4((k)+8) L2K4((k)+12)

// Shared L2 + folded L3 (64->64 relu -> dot w3), mb tiles of 16 rolled.
#define MLP_L2_FOLD(W2p, B2p, W3p) \
  _Pragma("unroll 1") \
  for (int mb = 0; mb < 4; ++mb) { \
      const float* w2base = (W2p) + mb*16; \
      float acc[16]; \
      LOAD16(acc, (B2p) + mb*16) \
      L2K16(0) L2K16(16) L2K16(32) L2K16(48) \
      const float* w3_ = (W3p) + mb*16; \
      FOLD16(w3_) \
  }

// ---------------- K1 v2: jet MLP, 4 lanes per jet ----------------
// 65536 jets x 4 lanes = 4096 waves (4/SIMD TLP, vs 1/SIMD in v1).
// Each lane: full h1[64] (redundant x4, +1% total FLOPs), then only its
// own 16-wide L2 output tile (sub = lane&3), quad-summed via 2 shuffles.
__global__ __launch_bounds__(256, 1)
void jet_mlp_kernel(const float* __restrict__ jet_inp,
                    const float* __restrict__ jW1, const float* __restrict__ jb1,
                    const float* __restrict__ jW2, const float* __restrict__ jb2,
                    const float* __restrict__ jW3, const float* __restrict__ jb3,
                    float* __restrict__ ws, int B)
{
    const int gid = blockIdx.x * 256 + threadIdx.x;
    const int jet = gid >> 2;
    const int sub = gid & 3;          // L2 output tile index (quad-local)
    if (jet >= B) return;
    const float* jp = jet_inp + (size_t)jet * 16;

    float h1[64];
#define L1TILE_K1(T) { \
    float acc[16]; \
    LOAD16(acc, jb1 + (T)*16) \
    const float* w1p = jW1 + (T)*16; \
    _Pragma("unroll 1") \
    for (int c = 0; c < 4; ++c) { \
        const float4 xv = *(const float4*)(jp + c*4); \
        L1CHUNK(xv) \
        w1p += 256; } \
    RELUST16(h1, (T)*16, acc) }
    L1TILE_K1(0) L1TILE_K1(1) L1TILE_K1(2) L1TILE_K1(3)
#undef L1TILE_K1

    float ts0 = 0.f, ts1 = 0.f;
    {
        const float* w2base = jW2 + sub*16;
        float acc[16];
        LOAD16(acc, jb2 + sub*16)
        L2K16(0) L2K16(16) L2K16(32) L2K16(48)
        const float* w3_ = jW3 + sub*16;
        FOLD16(w3_)
    }
    float t = ts0 + ts1;
    t += __shfl_xor(t, 1, 64);        // quad reduce (sub 0..3 are adjacent lanes)
    t += __shfl_xor(t, 2, 64);
    if (sub == 0) ws[jet] = sigmoid_fast(t + jb3[0]);
}

// ---------------- K2: neighbor streams (UNCHANGED from R11, the control) ----------------
__global__ __launch_bounds__(256, 1)
void neigh_streams_kernel(const float* __restrict__ jet_inp,
                          const float* __restrict__ neigh_inp,
                          const float* __restrict__ nW1, const float* __restrict__ nb1,
                          const float* __restrict__ nW2, const float* __restrict__ nb2,
                          const float* __restrict__ nW3, const float* __restrict__ nb3,
                          const float* __restrict__ jet_eff,
                          float* __restrict__ out, int B)
{
    const int lane = threadIdx.x & 63;
    const int half = lane >> 5;   // 0 = jet A, 1 = jet B
    const int nb   = lane & 31;   // neighbor index
    const int wid  = threadIdx.x >> 6;
    const int gw = blockIdx.x * 4 + wid;
    const int nw = gridDim.x * 4;
    const int npairs = B >> 1;
    const float bias3 = nb3[0];

    for (int pair = gw; pair < npairs; pair += nw) {
        const int jet = pair * 2 + half;
        const float* jp = jet_inp   + (size_t)jet * 16;
        const float* np = neigh_inp + (size_t)jet * (NNB*16) + (size_t)nb * 16;

        float h1[64];
        // L1: rows 0..15 = jet feats, rows 16..31 = neighbor feats (concat order).
#define L1TILE_K2(T) { \
        float acc[16]; \
        LOAD16(acc, nb1 + (T)*16) \
        const float* w1p = nW1 + (T)*16; \
        _Pragma("unroll 1") \
        for (int c = 0; c < 4; ++c) { \
            const float4 xv = *(const float4*)(jp + c*4); \
            L1CHUNK(xv) \
            w1p += 256; } \
        _Pragma("unroll 1") \
        for (int c = 0; c < 4; ++c) { \
            const float4 xv = *(const float4*)(np + c*4); \
            L1CHUNK(xv) \
            w1p += 256; } \
        RELUST16(h1, (T)*16, acc) }
        L1TILE_K2(0) L1TILE_K2(1) L1TILE_K2(2) L1TILE_K2(3)
#undef L1TILE_K2

        float ts0 = 0.f, ts1 = 0.f;
        MLP_L2_FOLD(nW2, nb2, nW3)
        const float t_n = ts0 + ts1 + bias3;

        // log-sigmoid, then 5-shuffle sum within each 32-lane half
        float ls = -__logf(1.0f + __expf(-t_n));
#pragma unroll
        for (int off = 16; off >= 1; off >>= 1)
            ls += __shfl_xor(ls, off, 64);
        const float corr = __expf(ls);

        if (nb == 0) out[jet] = jet_eff[jet] * corr;
    }
}

extern "C" void kernel_launch(void* const* d_in, const int* in_sizes, int n_in,
                              void* d_out, int out_size, void* d_ws, size_t ws_size,
                              hipStream_t stream) {
    const float* jet_inp = (const float*)d_in[0];
    const float* neigh   = (const float*)d_in[1];
    const float* jW1 = (const float*)d_in[2];
    const float* jb1 = (const float*)d_in[3];
    const float* jW2 = (const float*)d_in[4];
    const float* jb2 = (const float*)d_in[5];
    const float* jW3 = (const float*)d_in[6];
    const float* jb3 = (const float*)d_in[7];
    const float* nW1 = (const float*)d_in[8];
    const float* nb1 = (const float*)d_in[9];
    const float* nW2 = (const float*)d_in[10];
    const float* nb2 = (const float*)d_in[11];
    const float* nW3 = (const float*)d_in[12];
    const float* nb3 = (const float*)d_in[13];
    float* out = (float*)d_out;
    float* ws  = (float*)d_ws;
    const int B = in_sizes[0] / 16;

    hipLaunchKernelGGL(jet_mlp_kernel, dim3((B * 4 + 255) / 256), dim3(256), 0, stream,
                       jet_inp, jW1, jb1, jW2, jb2, jW3, jb3, ws, B);
    hipLaunchKernelGGL(neigh_streams_kernel, dim3(2048), dim3(256), 0, stream,
                       jet_inp, neigh, nW1, nb1, nW2, nb2, nW3, nb3,
                       ws, out, B);
}

// Round 14
// 563.565 us; speedup vs baseline: 1.0424x; 1.0424x over previous
//
#include <hip/hip_runtime.h>

#define NNB 32

__device__ __forceinline__ float sigmoid_fast(float x) {
    return __fdividef(1.0f, 1.0f + __expf(-x));
}

// ---- repetition macros: ALL register-array indices are compile-time
// literals (rule #20: runtime-indexed arrays go to scratch; literal-indexed
// arrays are SROA'd into scalars regardless of unroll heuristics). ----
#define LOAD16(a, s) \
  a[0]=(s)[0];   a[1]=(s)[1];   a[2]=(s)[2];   a[3]=(s)[3]; \
  a[4]=(s)[4];   a[5]=(s)[5];   a[6]=(s)[6];   a[7]=(s)[7]; \
  a[8]=(s)[8];   a[9]=(s)[9];   a[10]=(s)[10]; a[11]=(s)[11]; \
  a[12]=(s)[12]; a[13]=(s)[13]; a[14]=(s)[14]; a[15]=(s)[15];

#define FMA16(a, s, w) \
  a[0]=fmaf((s),(w)[0],a[0]);    a[1]=fmaf((s),(w)[1],a[1]); \
  a[2]=fmaf((s),(w)[2],a[2]);    a[3]=fmaf((s),(w)[3],a[3]); \
  a[4]=fmaf((s),(w)[4],a[4]);    a[5]=fmaf((s),(w)[5],a[5]); \
  a[6]=fmaf((s),(w)[6],a[6]);    a[7]=fmaf((s),(w)[7],a[7]); \
  a[8]=fmaf((s),(w)[8],a[8]);    a[9]=fmaf((s),(w)[9],a[9]); \
  a[10]=fmaf((s),(w)[10],a[10]); a[11]=fmaf((s),(w)[11],a[11]); \
  a[12]=fmaf((s),(w)[12],a[12]); a[13]=fmaf((s),(w)[13],a[13]); \
  a[14]=fmaf((s),(w)[14],a[14]); a[15]=fmaf((s),(w)[15],a[15]);

#define RELUST16(h, B, a) \
  h[(B)+0]=fmaxf(a[0],0.f);    h[(B)+1]=fmaxf(a[1],0.f); \
  h[(B)+2]=fmaxf(a[2],0.f);    h[(B)+3]=fmaxf(a[3],0.f); \
  h[(B)+4]=fmaxf(a[4],0.f);    h[(B)+5]=fmaxf(a[5],0.f); \
  h[(B)+6]=fmaxf(a[6],0.f);    h[(B)+7]=fmaxf(a[7],0.f); \
  h[(B)+8]=fmaxf(a[8],0.f);    h[(B)+9]=fmaxf(a[9],0.f); \
  h[(B)+10]=fmaxf(a[10],0.f);  h[(B)+11]=fmaxf(a[11],0.f); \
  h[(B)+12]=fmaxf(a[12],0.f);  h[(B)+13]=fmaxf(a[13],0.f); \
  h[(B)+14]=fmaxf(a[14],0.f);  h[(B)+15]=fmaxf(a[15],0.f);

#define FOLD16(w) \
  ts0=fmaf(fmaxf(acc[0],0.f),(w)[0],ts0);   ts1=fmaf(fmaxf(acc[1],0.f),(w)[1],ts1); \
  ts0=fmaf(fmaxf(acc[2],0.f),(w)[2],ts0);   ts1=fmaf(fmaxf(acc[3],0.f),(w)[3],ts1); \
  ts0=fmaf(fmaxf(acc[4],0.f),(w)[4],ts0);   ts1=fmaf(fmaxf(acc[5],0.f),(w)[5],ts1); \
  ts0=fmaf(fmaxf(acc[6],0.f),(w)[6],ts0);   ts1=fmaf(fmaxf(acc[7],0.f),(w)[7],ts1); \
  ts0=fmaf(fmaxf(acc[8],0.f),(w)[8],ts0);   ts1=fmaf(fmaxf(acc[9],0.f),(w)[9],ts1); \
  ts0=fmaf(fmaxf(acc[10],0.f),(w)[10],ts0); ts1=fmaf(fmaxf(acc[11],0.f),(w)[11],ts1); \
  ts0=fmaf(fmaxf(acc[12],0.f),(w)[12],ts0); ts1=fmaf(fmaxf(acc[13],0.f),(w)[13],ts1); \
  ts0=fmaf(fmaxf(acc[14],0.f),(w)[14],ts0); ts1=fmaf(fmaxf(acc[15],0.f),(w)[15],ts1);

// 4 k-steps consuming one float4 of input; weights advance 64 floats/row.
#define L1CHUNK(xv) \
  { const float* w_=w1p;     FMA16(acc,(xv).x,w_) } \
  { const float* w_=w1p+64;  FMA16(acc,(xv).y,w_) } \
  { const float* w_=w1p+128; FMA16(acc,(xv).z,w_) } \
  { const float* w_=w1p+192; FMA16(acc,(xv).w,w_) }

// L2 k-step: h1[(k)] is a literal index.
#define L2K(k)   { const float* w_=w2base+(k)*64; FMA16(acc, h1[(k)], w_) }
#define L2K4(k)  L2K(k) L2K((k)+1) L2K((k)+2) L2K((k)+3)
#define L2K16(k) L2K4(k) L2K4((k)+4) L2K4((k)+8) L2K4((k)+12)

// Shared L2 + folded L3 (64->64 relu -> dot w3), mb tiles of 16 rolled.
#define MLP_L2_FOLD(W2p, B2p, W3p) \
  _Pragma("unroll 1") \
  for (int mb = 0; mb < 4; ++mb) { \
      const float* w2base = (W2p) + mb*16; \
      float acc[16]; \
      LOAD16(acc, (B2p) + mb*16) \
      L2K16(0) L2K16(16) L2K16(32) L2K16(48) \
      const float* w3_ = (W3p) + mb*16; \
      FOLD16(w3_) \
  }

// ---------------- K1 v3: jet MLP, wave = mb tile, lane = jet ----------------
// Block = 4 waves covering 64 jets. lane indexes the jet (so WEIGHT addresses
// stay wave-uniform -> s_load; the v2 regression was per-lane weight addrs).
// wid = which 16-wide L2 output tile this wave computes (wave-uniform).
// Each wave redundantly computes h1[64] for its lane's jet (+1.5% work),
// then its own L2 tile; 4 partials combine through LDS (stride-1, no
// conflicts). 1024 blocks -> 4096 waves -> 4 waves/SIMD TLP.
__global__ __launch_bounds__(256, 1)
void jet_mlp_kernel(const float* __restrict__ jet_inp,
                    const float* __restrict__ jW1, const float* __restrict__ jb1,
                    const float* __restrict__ jW2, const float* __restrict__ jb2,
                    const float* __restrict__ jW3, const float* __restrict__ jb3,
                    float* __restrict__ ws, int B)
{
    const int lane = threadIdx.x & 63;
    const int wid  = threadIdx.x >> 6;          // mb tile, wave-uniform
    const int jet  = blockIdx.x * 64 + lane;
    __shared__ float s_part[4][64];

    float tval = 0.f;
    if (jet < B) {
        const float* jp = jet_inp + (size_t)jet * 16;
        float h1[64];
#define L1TILE_K1(T) { \
        float acc[16]; \
        LOAD16(acc, jb1 + (T)*16) \
        const float* w1p = jW1 + (T)*16; \
        _Pragma("unroll 1") \
        for (int c = 0; c < 4; ++c) { \
            const float4 xv = *(const float4*)(jp + c*4); \
            L1CHUNK(xv) \
            w1p += 256; } \
        RELUST16(h1, (T)*16, acc) }
        L1TILE_K1(0) L1TILE_K1(1) L1TILE_K1(2) L1TILE_K1(3)
#undef L1TILE_K1

        float ts0 = 0.f, ts1 = 0.f;
        {
            const float* w2base = jW2 + wid*16;     // wave-uniform
            float acc[16];
            LOAD16(acc, jb2 + wid*16)
            L2K16(0) L2K16(16) L2K16(32) L2K16(48)
            const float* w3_ = jW3 + wid*16;
            FOLD16(w3_)
        }
        tval = ts0 + ts1;
    }
    s_part[wid][lane] = tval;
    __syncthreads();
    if (wid == 0 && jet < B) {
        float t = s_part[0][lane] + s_part[1][lane]
                + s_part[2][lane] + s_part[3][lane];
        ws[jet] = sigmoid_fast(t + jb3[0]);
    }
}

// ---------------- K2: neighbor streams (UNCHANGED from R11/R12, the control) ----------------
__global__ __launch_bounds__(256, 1)
void neigh_streams_kernel(const float* __restrict__ jet_inp,
                          const float* __restrict__ neigh_inp,
                          const float* __restrict__ nW1, const float* __restrict__ nb1,
                          const float* __restrict__ nW2, const float* __restrict__ nb2,
                          const float* __restrict__ nW3, const float* __restrict__ nb3,
                          const float* __restrict__ jet_eff,
                          float* __restrict__ out, int B)
{
    const int lane = threadIdx.x & 63;
    const int half = lane >> 5;   // 0 = jet A, 1 = jet B
    const int nb   = lane & 31;   // neighbor index
    const int wid  = threadIdx.x >> 6;
    const int gw = blockIdx.x * 4 + wid;
    const int nw = gridDim.x * 4;
    const int npairs = B >> 1;
    const float bias3 = nb3[0];

    for (int pair = gw; pair < npairs; pair += nw) {
        const int jet = pair * 2 + half;
        const float* jp = jet_inp   + (size_t)jet * 16;
        const float* np = neigh_inp + (size_t)jet * (NNB*16) + (size_t)nb * 16;

        float h1[64];
        // L1: rows 0..15 = jet feats, rows 16..31 = neighbor feats (concat order).
#define L1TILE_K2(T) { \
        float acc[16]; \
        LOAD16(acc, nb1 + (T)*16) \
        const float* w1p = nW1 + (T)*16; \
        _Pragma("unroll 1") \
        for (int c = 0; c < 4; ++c) { \
            const float4 xv = *(const float4*)(jp + c*4); \
            L1CHUNK(xv) \
            w1p += 256; } \
        _Pragma("unroll 1") \
        for (int c = 0; c < 4; ++c) { \
            const float4 xv = *(const float4*)(np + c*4); \
            L1CHUNK(xv) \
            w1p += 256; } \
        RELUST16(h1, (T)*16, acc) }
        L1TILE_K2(0) L1TILE_K2(1) L1TILE_K2(2) L1TILE_K2(3)
#undef L1TILE_K2

        float ts0 = 0.f, ts1 = 0.f;
        MLP_L2_FOLD(nW2, nb2, nW3)
        const float t_n = ts0 + ts1 + bias3;

        // log-sigmoid, then 5-shuffle sum within each 32-lane half
        float ls = -__logf(1.0f + __expf(-t_n));
#pragma unroll
        for (int off = 16; off >= 1; off >>= 1)
            ls += __shfl_xor(ls, off, 64);
        const float corr = __expf(ls);

        if (nb == 0) out[jet] = jet_eff[jet] * corr;
    }
}

extern "C" void kernel_launch(void* const* d_in, const int* in_sizes, int n_in,
                              void* d_out, int out_size, void* d_ws, size_t ws_size,
                              hipStream_t stream) {
    const float* jet_inp = (const float*)d_in[0];
    const float* neigh   = (const float*)d_in[1];
    const float* jW1 = (const float*)d_in[2];
    const float* jb1 = (const float*)d_in[3];
    const float* jW2 = (const float*)d_in[4];
    const float* jb2 = (const float*)d_in[5];
    const float* jW3 = (const float*)d_in[6];
    const float* jb3 = (const float*)d_in[7];
    const float* nW1 = (const float*)d_in[8];
    const float* nb1 = (const float*)d_in[9];
    const float* nW2 = (const float*)d_in[10];
    const float* nb2 = (const float*)d_in[11];
    const float* nW3 = (const float*)d_in[12];
    const float* nb3 = (const float*)d_in[13];
    float* out = (float*)d_out;
    float* ws  = (float*)d_ws;
    const int B = in_sizes[0] / 16;

    hipLaunchKernelGGL(jet_mlp_kernel, dim3((B + 63) / 64), dim3(256), 0, stream,
                       jet_inp, jW1, jb1, jW2, jb2, jW3, jb3, ws, B);
    hipLaunchKernelGGL(neigh_streams_kernel, dim3(2048), dim3(256), 0, stream,
                       jet_inp, neigh, nW1, nb1, nW2, nb2, nW3, nb3,
                       ws, out, B);
}